// Round 9
// baseline (974.551 us; speedup 1.0000x reference)
//
#include <hip/hip_runtime.h>
#include <math.h>

#define BATCH 4096
#define D 784
#define N 10000

#define KP 800                 // padded K (halves)
#define KT 25                  // K steps of 32
#define NPAD 10240             // 40 * 256
#define GX 40                  // col groups of 256 (2 chunks of 128)
#define NG 40
#define MARGIN 3.0f

typedef __attribute__((ext_vector_type(8))) short bh8;
typedef __attribute__((ext_vector_type(4))) float fx4;

static __device__ __forceinline__ unsigned short f2bf(float f) {
    unsigned u = __float_as_uint(f);
    unsigned r = u + 0x7fffu + ((u >> 16) & 1u);
    return (unsigned short)(r >> 16);
}

static __device__ __forceinline__ void top2_insert(float w, int j, float& v0, int& i0,
                                                   float& v1, int& i1) {
    if (w < v0 || (w == v0 && j < i0)) { v1 = v0; i1 = i0; v0 = w; i0 = j; }
    else if (w < v1 || (w == v1 && j < i1)) { v1 = w; i1 = j; }
}

// ---------------------------------------------------------------------------
__global__ __launch_bounds__(256) void convert_x_kernel(const float* __restrict__ x,
                                                        unsigned short* __restrict__ xh) {
    int row = blockIdx.x;
    const float4* xr = (const float4*)(x + (size_t)row * D);
    unsigned short* dst = xh + (size_t)row * KP;
    for (int i = threadIdx.x; i < KP / 4; i += 256) {
        int k = i * 4;
        uint2 o;
        if (k < D) {
            float4 v = xr[i];
            o.x = (unsigned)f2bf(v.x) | ((unsigned)f2bf(v.y) << 16);
            o.y = (unsigned)f2bf(v.z) | ((unsigned)f2bf(v.w) << 16);
        } else { o.x = 0u; o.y = 0u; }
        *(uint2*)(dst + k) = o;
    }
}

__global__ __launch_bounds__(256) void convert_w_kernel(const float* __restrict__ w,
                                                        unsigned short* __restrict__ wh,
                                                        float* __restrict__ wsq) {
    int row = blockIdx.x;
    unsigned short* dst = wh + (size_t)row * KP;
    float s = 0.f;
    if (row < N) {
        const float4* wr = (const float4*)(w + (size_t)row * D);
        for (int i = threadIdx.x; i < KP / 4; i += 256) {
            int k = i * 4;
            uint2 o;
            if (k < D) {
                float4 v = wr[i];
                s += v.x * v.x + v.y * v.y + v.z * v.z + v.w * v.w;
                o.x = (unsigned)f2bf(v.x) | ((unsigned)f2bf(v.y) << 16);
                o.y = (unsigned)f2bf(v.z) | ((unsigned)f2bf(v.w) << 16);
            } else { o.x = 0u; o.y = 0u; }
            *(uint2*)(dst + k) = o;
        }
    } else {
        for (int i = threadIdx.x; i < KP / 4; i += 256) {
            uint2 o; o.x = 0u; o.y = 0u;
            *(uint2*)(dst + i * 4) = o;
        }
    }
    __shared__ float sred[4];
    #pragma unroll
    for (int off = 32; off; off >>= 1) s += __shfl_down(s, off);
    if ((threadIdx.x & 63) == 0) sred[threadIdx.x >> 6] = s;
    __syncthreads();
    if (threadIdx.x == 0) {
        float t = sred[0] + sred[1] + sred[2] + sred[3];
        wsq[row] = (row < N) ? t : INFINITY;
    }
}

// ---------------------------------------------------------------------------
// Direct-from-global MFMA distance kernel. NO LDS staging, NO barriers, NO
// waitcnt asm in the K-loop. 4 waves (2Mx2N), 128x128 per chunk, 2 chunks.
// Fragments global->reg with base+imm addressing; 2-deep reg pipeline;
// compiler schedules all waits. Fragment layout identical to proven kernels.
// ---------------------------------------------------------------------------
__global__ __launch_bounds__(256) void dist_direct_kernel(
    const unsigned short* __restrict__ xh, const unsigned short* __restrict__ wh,
    const float* __restrict__ wsq, float4* __restrict__ partial) {
    __shared__ float4 red[128][2];

    const int tid = threadIdx.x;
    const int lane = tid & 63;
    const int wid = tid >> 6;
    const int waveM = (wid >> 1) * 64;
    const int waveN = (wid & 1) * 64;

    // XCD remap: nwg=1280, bijective. XCD owns 4 row-panels, sweeps bx;
    // 4 consecutive slots share bx (B-panel 200 KB L2-hot).
    const int L = blockIdx.x + GX * blockIdx.y;
    const int xcd = L & 7;
    const int s = L >> 3;                // 0..159
    const int bx = s >> 2;               // 0..39
    const int by = xcd * 4 + (s & 3);    // 0..31
    const int rowBase = by * 128;
    const int colBase0 = bx * 256;

    // per-lane A fragment bases (row-major, 16B per lane per step)
    const unsigned short* pa[4];
    #pragma unroll
    for (int m = 0; m < 4; m++) {
        int r = rowBase + waveM + m * 16 + (lane & 15);
        pa[m] = xh + (size_t)r * KP + (lane >> 4) * 8;
    }

    // running per-lane top-2 for 16 (m,r) rows across both chunks
    float V0[16], V1[16];
    int I0[16], I1[16];
    #pragma unroll
    for (int q = 0; q < 16; q++) {
        V0[q] = INFINITY; V1[q] = INFINITY;
        I0[q] = 0x7fffffff; I1[q] = 0x7fffffff;
    }

    #pragma unroll 1
    for (int c = 0; c < 2; ++c) {
        const int colBase = colBase0 + c * 128;
        const unsigned short* pb[4];
        #pragma unroll
        for (int n = 0; n < 4; n++) {
            int r = colBase + waveN + n * 16 + (lane & 15);
            pb[n] = wh + (size_t)r * KP + (lane >> 4) * 8;
        }

        fx4 acc[4][4];
        #pragma unroll
        for (int m = 0; m < 4; m++)
            #pragma unroll
            for (int n = 0; n < 4; n++) acc[m][n] = (fx4)0.f;

        // 2-deep register pipeline over 25 fully-unrolled K-steps
        bh8 ca[4], cb[4];
        #pragma unroll
        for (int m = 0; m < 4; m++) ca[m] = *(const bh8*)(pa[m]);
        #pragma unroll
        for (int n = 0; n < 4; n++) cb[n] = *(const bh8*)(pb[n]);

        #pragma unroll
        for (int t = 0; t < KT; ++t) {
            bh8 na[4], nb[4];
            if (t + 1 < KT) {
                #pragma unroll
                for (int m = 0; m < 4; m++) na[m] = *(const bh8*)(pa[m] + (t + 1) * 32);
                #pragma unroll
                for (int n = 0; n < 4; n++) nb[n] = *(const bh8*)(pb[n] + (t + 1) * 32);
            }
            #pragma unroll
            for (int m = 0; m < 4; m++)
                #pragma unroll
                for (int n = 0; n < 4; n++)
                    acc[m][n] = __builtin_amdgcn_mfma_f32_16x16x32_bf16(ca[m], cb[n],
                                                                        acc[m][n], 0, 0, 0);
            if (t + 1 < KT) {
                #pragma unroll
                for (int m = 0; m < 4; m++) ca[m] = na[m];
                #pragma unroll
                for (int n = 0; n < 4; n++) cb[n] = nb[n];
            }
        }

        // fold this chunk into register top-2
        const int cbase = colBase + waveN + (lane & 15);
        #pragma unroll
        for (int n = 0; n < 4; n++) {
            const float wq = wsq[cbase + n * 16];
            const int ci = cbase + n * 16;
            #pragma unroll
            for (int m = 0; m < 4; m++)
                #pragma unroll
                for (int r = 0; r < 4; r++) {
                    float dv = wq - 2.f * acc[m][n][r];
                    top2_insert(dv, ci, V0[m * 4 + r], I0[m * 4 + r],
                                V1[m * 4 + r], I1[m * 4 + r]);
                }
        }
    }

    // cross-lane reduce + cross-wave combine (r3-proven epilogue)
    #pragma unroll
    for (int q = 0; q < 16; q++) {
        float v0 = V0[q], v1 = V1[q];
        int i0 = I0[q], i1 = I1[q];
        #pragma unroll
        for (int mask = 1; mask < 16; mask <<= 1) {
            float w0 = __shfl_xor(v0, mask); int j0 = __shfl_xor(i0, mask);
            float w1 = __shfl_xor(v1, mask); int j1 = __shfl_xor(i1, mask);
            top2_insert(w0, j0, v0, i0, v1, i1);
            top2_insert(w1, j1, v0, i0, v1, i1);
        }
        if ((lane & 15) == 0) {
            int m = q >> 2, r = q & 3;
            int row_local = waveM + m * 16 + (lane >> 4) * 4 + r;
            red[row_local][wid & 1] =
                make_float4(v0, __int_as_float(i0), v1, __int_as_float(i1));
        }
    }
    __syncthreads();
    if (tid < 128) {
        float4 pa4 = red[tid][0], pb4 = red[tid][1];
        float v0 = pa4.x, v1 = pa4.z;
        int i0 = __float_as_int(pa4.y), i1 = __float_as_int(pa4.w);
        top2_insert(pb4.x, __float_as_int(pb4.y), v0, i0, v1, i1);
        top2_insert(pb4.z, __float_as_int(pb4.w), v0, i0, v1, i1);
        partial[(size_t)(rowBase + tid) * NG + bx] =
            make_float4(v0, __int_as_float(i0), v1, __int_as_float(i1));
    }
}

// ---------------------------------------------------------------------------
// Rescue: fp64 rescore of all candidates within MARGIN of approx global min.
// ---------------------------------------------------------------------------
__global__ __launch_bounds__(256) void rescore_kernel(const float* __restrict__ x,
                                                      const float* __restrict__ w,
                                                      const float4* __restrict__ partial,
                                                      float* __restrict__ out, int ng) {
    int wid = threadIdx.x >> 6, lane = threadIdx.x & 63;
    int row = blockIdx.x * 4 + wid;
    __shared__ int s_cnt[4];
    __shared__ int s_cand[4][64];

    const float4* part = partial + (size_t)row * ng;

    float bv = INFINITY;
    for (int c = lane; c < ng; c += 64) bv = fminf(bv, part[c].x);
    #pragma unroll
    for (int mask = 1; mask < 64; mask <<= 1) bv = fminf(bv, __shfl_xor(bv, mask));
    float thr = bv + MARGIN;

    if (lane == 0) s_cnt[wid] = 0;
    __syncthreads();
    for (int c = lane; c < ng; c += 64) {
        float4 p = part[c];
        if (p.x <= thr) {
            int pos = atomicAdd(&s_cnt[wid], 1);
            if (pos < 64) s_cand[wid][pos] = __float_as_int(p.y);
        }
        if (p.z <= thr) {
            int pos = atomicAdd(&s_cnt[wid], 1);
            if (pos < 64) s_cand[wid][pos] = __float_as_int(p.w);
        }
    }
    __syncthreads();
    int cnt = s_cnt[wid]; if (cnt > 64) cnt = 64;

    double bd = INFINITY; int bi = 0x7fffffff;
    for (int c = 0; c < cnt; c++) {
        int idx = s_cand[wid][c];
        const float* wr = w + (size_t)idx * D;
        const float* xr = x + (size_t)row * D;
        double s = 0.0;
        for (int d = lane; d < D; d += 64) {
            double wv = (double)wr[d];
            s += wv * (wv - 2.0 * (double)xr[d]);
        }
        #pragma unroll
        for (int mask = 1; mask < 64; mask <<= 1) s += __shfl_xor(s, mask);
        if (s < bd || (s == bd && idx < bi)) { bd = s; bi = idx; }
    }

    const float4* src = (const float4*)(w + (size_t)bi * D);
    float4* dst = (float4*)(out + (size_t)row * D);
    for (int i = lane; i < D / 4; i += 64) dst[i] = src[i];
}

// ---------------------------------------------------------------------------
extern "C" void kernel_launch(void* const* d_in, const int* in_sizes, int n_in,
                              void* d_out, int out_size, void* d_ws, size_t ws_size,
                              hipStream_t stream) {
    const float* x = (const float*)d_in[0];
    const float* w = (const float*)d_in[1];
    float* out = (float*)d_out;

    const size_t off_xh = 0;
    const size_t off_wh = off_xh + (size_t)BATCH * KP * 2;     // 6,553,600
    const size_t off_wsq = off_wh + (size_t)NPAD * KP * 2;     // +16,384,000
    const size_t off_part = off_wsq + (size_t)NPAD * 4;        // +40,960
    // need = off_part + 4096*40*16 = 25,600,000 (proven in r7/r8)

    unsigned short* xh = (unsigned short*)((char*)d_ws + off_xh);
    unsigned short* wh = (unsigned short*)((char*)d_ws + off_wh);
    float* wsq = (float*)((char*)d_ws + off_wsq);
    float4* partial = (float4*)((char*)d_ws + off_part);

    hipLaunchKernelGGL(convert_x_kernel, dim3(BATCH), dim3(256), 0, stream, x, xh);
    hipLaunchKernelGGL(convert_w_kernel, dim3(NPAD), dim3(256), 0, stream, w, wh, wsq);
    hipLaunchKernelGGL(dist_direct_kernel, dim3(GX, 32), dim3(256), 0, stream,
                       xh, wh, wsq, partial);
    hipLaunchKernelGGL(rescore_kernel, dim3(BATCH / 4), dim3(256), 0, stream,
                       x, w, partial, out, NG);
}

// Round 10
// 666.583 us; speedup vs baseline: 1.4620x; 1.4620x over previous
//
#include <hip/hip_runtime.h>
#include <math.h>

#define BATCH 4096
#define D 784
#define N 10000

#define KP2 400                // padded K in f16-PAIRS (uints) per row
#define KC 16                  // uint-k per chunk
#define NCH (KP2 / KC)         // 25 chunks per 128-col pass
#define NG 40                  // col groups of 256 (2 passes of 128)
#define NPAD (NG * 256)        // 10240
#define MARGIN 3.0f

typedef _Float16 h2v __attribute__((ext_vector_type(2)));

#if defined(__has_builtin)
#if __has_builtin(__builtin_amdgcn_fdot2)
#define HAVE_FDOT2 1
#endif
#endif

static __device__ __forceinline__ float dot2acc(unsigned a, unsigned b, float c) {
#ifdef HAVE_FDOT2
    return __builtin_amdgcn_fdot2(__builtin_bit_cast(h2v, a),
                                  __builtin_bit_cast(h2v, b), c, false);
#else
    h2v ha = __builtin_bit_cast(h2v, a), hb = __builtin_bit_cast(h2v, b);
    return c + (float)ha[0] * (float)hb[0] + (float)ha[1] * (float)hb[1];
#endif
}

static __device__ __forceinline__ unsigned short f2h(float f) {
    _Float16 h = (_Float16)f;
    return __builtin_bit_cast(unsigned short, h);
}

static __device__ __forceinline__ void top2_insert(float w, int j, float& v0, int& i0,
                                                   float& v1, int& i1) {
    if (w < v0 || (w == v0 && j < i0)) { v1 = v0; i1 = i0; v0 = w; i0 = j; }
    else if (w < v1 || (w == v1 && j < i1)) { v1 = w; i1 = j; }
}

// ---------------------------------------------------------------------------
// convert x -> packed f16 pairs (row-major [4096][400] uints), K zero-padded
// ---------------------------------------------------------------------------
__global__ __launch_bounds__(256) void convert_x_kernel(const float* __restrict__ x,
                                                        unsigned* __restrict__ xh2) {
    int row = blockIdx.x;
    const float* xr = x + (size_t)row * D;
    unsigned* dst = xh2 + (size_t)row * KP2;
    for (int i = threadIdx.x; i < KP2; i += 256) {
        int k = i * 2;
        unsigned o = 0u;
        if (k < D) {
            float2 v = *(const float2*)(xr + k);   // D even, 8B-aligned
            o = (unsigned)f2h(v.x) | ((unsigned)f2h(v.y) << 16);
        }
        dst[i] = o;
    }
}

// ---------------------------------------------------------------------------
// convert w -> packed f16 pairs [10240][400] + fp32 wsq (pad rows = +INF)
// ---------------------------------------------------------------------------
__global__ __launch_bounds__(256) void convert_w_kernel(const float* __restrict__ w,
                                                        unsigned* __restrict__ wh2,
                                                        float* __restrict__ wsq) {
    int row = blockIdx.x;
    unsigned* dst = wh2 + (size_t)row * KP2;
    float s = 0.f;
    if (row < N) {
        const float* wr = w + (size_t)row * D;
        for (int i = threadIdx.x; i < KP2; i += 256) {
            int k = i * 2;
            unsigned o = 0u;
            if (k < D) {
                float2 v = *(const float2*)(wr + k);
                s += v.x * v.x + v.y * v.y;
                o = (unsigned)f2h(v.x) | ((unsigned)f2h(v.y) << 16);
            }
            dst[i] = o;
        }
    } else {
        for (int i = threadIdx.x; i < KP2; i += 256) dst[i] = 0u;
    }
    __shared__ float sred[4];
    #pragma unroll
    for (int off = 32; off; off >>= 1) s += __shfl_down(s, off);
    if ((threadIdx.x & 63) == 0) sred[threadIdx.x >> 6] = s;
    __syncthreads();
    if (threadIdx.x == 0) {
        float t = sred[0] + sred[1] + sred[2] + sred[3];
        wsq[row] = (row < N) ? t : INFINITY;
    }
}

// ---------------------------------------------------------------------------
// dot2-f16 distance kernel, modeled on the round-1 85%-VALUBusy structure.
// 64x128 tile, 256 threads, 4x8 outputs/thread, k-major LDS (conflict-free),
// 2 col-passes/block, register top-2, single writer per row per block.
// ---------------------------------------------------------------------------
__global__ __launch_bounds__(256) void dist_dot2_kernel(
    const unsigned* __restrict__ xh2, const unsigned* __restrict__ wh2,
    const float* __restrict__ wsq, float4* __restrict__ partial) {
    __shared__ unsigned xs[KC][68];    // k-major A tile (uints of 2 halves)
    __shared__ unsigned ws[KC][132];   // k-major B tile

    const int tid = threadIdx.x;
    const int tr = tid >> 4;           // 0..15: rows tr*4..tr*4+3
    const int tc = tid & 15;           // 0..15: cols {tc*4+j, 64+tc*4+j}

    // XCD remap: 2560 blocks, bijective; XCD owns 8 row-groups (410 KB A),
    // sweeps bx with 8 same-bx blocks co-resident (B panel 205 KB shared).
    const int L = blockIdx.x + NG * blockIdx.y;
    const int xcd = L & 7;
    const int s = L >> 3;              // 0..319
    const int bx = s >> 3;             // 0..39
    const int by = xcd * 8 + (s & 7);  // 0..63
    const int rowBase = by * 64;
    const int colBase0 = bx * 256;

    const int xrow = tid >> 2, xseg = tid & 3;      // A staging
    const int brow = tid >> 1, bseg = tid & 1;      // B staging
    const unsigned* aSrc = xh2 + (size_t)(rowBase + xrow) * KP2 + xseg * 4;

    // running top-2 for this thread's 4 rows (across both passes)
    float V0[4], V1[4];
    int I0[4], I1[4];
    #pragma unroll
    for (int i = 0; i < 4; i++) {
        V0[i] = INFINITY; V1[i] = INFINITY;
        I0[i] = 0x7fffffff; I1[i] = 0x7fffffff;
    }

    #pragma unroll 1
    for (int c = 0; c < 2; ++c) {
        const int colBase = colBase0 + c * 128;
        const unsigned* bSrc = wh2 + (size_t)(colBase + brow) * KP2 + bseg * 8;

        float acc[4][8];
        #pragma unroll
        for (int i = 0; i < 4; i++)
            #pragma unroll
            for (int j = 0; j < 8; j++) acc[i][j] = 0.f;

        #pragma unroll 1
        for (int ch = 0; ch < NCH; ++ch) {
            const int k0 = ch * KC;
            // global -> regs
            uint4 va = *(const uint4*)(aSrc + k0);
            uint4 vb0 = *(const uint4*)(bSrc + k0);
            uint4 vb1 = *(const uint4*)(bSrc + k0 + 4);
            __syncthreads();   // previous chunk's LDS reads done
            // transpose-store to k-major (<=2-way banks, free)
            xs[xseg * 4 + 0][xrow] = va.x;
            xs[xseg * 4 + 1][xrow] = va.y;
            xs[xseg * 4 + 2][xrow] = va.z;
            xs[xseg * 4 + 3][xrow] = va.w;
            ws[bseg * 8 + 0][brow] = vb0.x;
            ws[bseg * 8 + 1][brow] = vb0.y;
            ws[bseg * 8 + 2][brow] = vb0.z;
            ws[bseg * 8 + 3][brow] = vb0.w;
            ws[bseg * 8 + 4][brow] = vb1.x;
            ws[bseg * 8 + 5][brow] = vb1.y;
            ws[bseg * 8 + 6][brow] = vb1.z;
            ws[bseg * 8 + 7][brow] = vb1.w;
            __syncthreads();
            // 16 k-units x 32 dot2
            #pragma unroll
            for (int k = 0; k < KC; k++) {
                uint4 a4 = *(const uint4*)&xs[k][tr * 4];       // broadcast
                uint4 b0 = *(const uint4*)&ws[k][tc * 4];       // 2-way free
                uint4 b1 = *(const uint4*)&ws[k][64 + tc * 4];  // 2-way free
                unsigned av[4] = {a4.x, a4.y, a4.z, a4.w};
                unsigned bv[8] = {b0.x, b0.y, b0.z, b0.w, b1.x, b1.y, b1.z, b1.w};
                #pragma unroll
                for (int i = 0; i < 4; i++)
                    #pragma unroll
                    for (int j = 0; j < 8; j++)
                        acc[i][j] = dot2acc(av[i], bv[j], acc[i][j]);
            }
        }

        // fold pass into register top-2
        #pragma unroll
        for (int j = 0; j < 8; j++) {
            const int col = colBase + (j >> 2) * 64 + tc * 4 + (j & 3);
            const float wq = wsq[col];
            #pragma unroll
            for (int i = 0; i < 4; i++) {
                float dv = wq - 2.f * acc[i][j];
                top2_insert(dv, col, V0[i], I0[i], V1[i], I1[i]);
            }
        }
        __syncthreads();   // LDS reads done before next pass restages
    }

    // reduce across the 16 tc-lanes; single writer per row per block
    #pragma unroll
    for (int mask = 1; mask < 16; mask <<= 1) {
        #pragma unroll
        for (int i = 0; i < 4; i++) {
            float w0 = __shfl_xor(V0[i], mask); int j0 = __shfl_xor(I0[i], mask);
            float w1 = __shfl_xor(V1[i], mask); int j1 = __shfl_xor(I1[i], mask);
            top2_insert(w0, j0, V0[i], I0[i], V1[i], I1[i]);
            top2_insert(w1, j1, V0[i], I0[i], V1[i], I1[i]);
        }
    }
    if (tc == 0) {
        #pragma unroll
        for (int i = 0; i < 4; i++) {
            int row = rowBase + tr * 4 + i;
            partial[(size_t)row * NG + bx] =
                make_float4(V0[i], __int_as_float(I0[i]), V1[i], __int_as_float(I1[i]));
        }
    }
}

// ---------------------------------------------------------------------------
// Rescue: fp64 rescore of all candidates within MARGIN of approx global min.
// ---------------------------------------------------------------------------
__global__ __launch_bounds__(256) void rescore_kernel(const float* __restrict__ x,
                                                      const float* __restrict__ w,
                                                      const float4* __restrict__ partial,
                                                      float* __restrict__ out, int ng) {
    int wid = threadIdx.x >> 6, lane = threadIdx.x & 63;
    int row = blockIdx.x * 4 + wid;
    __shared__ int s_cnt[4];
    __shared__ int s_cand[4][64];

    const float4* part = partial + (size_t)row * ng;

    float bv = INFINITY;
    for (int c = lane; c < ng; c += 64) bv = fminf(bv, part[c].x);
    #pragma unroll
    for (int mask = 1; mask < 64; mask <<= 1) bv = fminf(bv, __shfl_xor(bv, mask));
    float thr = bv + MARGIN;

    if (lane == 0) s_cnt[wid] = 0;
    __syncthreads();
    for (int c = lane; c < ng; c += 64) {
        float4 p = part[c];
        if (p.x <= thr) {
            int pos = atomicAdd(&s_cnt[wid], 1);
            if (pos < 64) s_cand[wid][pos] = __float_as_int(p.y);
        }
        if (p.z <= thr) {
            int pos = atomicAdd(&s_cnt[wid], 1);
            if (pos < 64) s_cand[wid][pos] = __float_as_int(p.w);
        }
    }
    __syncthreads();
    int cnt = s_cnt[wid]; if (cnt > 64) cnt = 64;

    double bd = INFINITY; int bi = 0x7fffffff;
    for (int c = 0; c < cnt; c++) {
        int idx = s_cand[wid][c];
        const float* wr = w + (size_t)idx * D;
        const float* xr = x + (size_t)row * D;
        double s = 0.0;
        for (int d = lane; d < D; d += 64) {
            double wv = (double)wr[d];
            s += wv * (wv - 2.0 * (double)xr[d]);
        }
        #pragma unroll
        for (int mask = 1; mask < 64; mask <<= 1) s += __shfl_xor(s, mask);
        if (s < bd || (s == bd && idx < bi)) { bd = s; bi = idx; }
    }

    const float4* src = (const float4*)(w + (size_t)bi * D);
    float4* dst = (float4*)(out + (size_t)row * D);
    for (int i = lane; i < D / 4; i += 64) dst[i] = src[i];
}

// ---------------------------------------------------------------------------
extern "C" void kernel_launch(void* const* d_in, const int* in_sizes, int n_in,
                              void* d_out, int out_size, void* d_ws, size_t ws_size,
                              hipStream_t stream) {
    const float* x = (const float*)d_in[0];
    const float* w = (const float*)d_in[1];
    float* out = (float*)d_out;

    const size_t off_xh2 = 0;                                   // 4096*400*4
    const size_t off_wh2 = off_xh2 + (size_t)BATCH * KP2 * 4;   // 6,553,600
    const size_t off_wsq = off_wh2 + (size_t)NPAD * KP2 * 4;    // +16,384,000
    const size_t off_part = off_wsq + (size_t)NPAD * 4;         // +40,960
    // need = off_part + 4096*40*16 = 25,600,000 (footprint proven in r7/r8)

    unsigned* xh2 = (unsigned*)((char*)d_ws + off_xh2);
    unsigned* wh2 = (unsigned*)((char*)d_ws + off_wh2);
    float* wsq = (float*)((char*)d_ws + off_wsq);
    float4* partial = (float4*)((char*)d_ws + off_part);

    hipLaunchKernelGGL(convert_x_kernel, dim3(BATCH), dim3(256), 0, stream, x, xh2);
    hipLaunchKernelGGL(convert_w_kernel, dim3(NPAD), dim3(256), 0, stream, w, wh2, wsq);
    hipLaunchKernelGGL(dist_dot2_kernel, dim3(NG, 64), dim3(256), 0, stream,
                       xh2, wh2, wsq, partial);
    hipLaunchKernelGGL(rescore_kernel, dim3(BATCH / 4), dim3(256), 0, stream,
                       x, w, partial, out, NG);
}

// Round 11
// 489.292 us; speedup vs baseline: 1.9918x; 1.3623x over previous
//
#include <hip/hip_runtime.h>
#include <math.h>

#define BATCH 4096
#define D 784
#define N 10000

#define KP 800                 // padded K (halves)
#define BK 32                  // K-step (halves)
#define KT (KP / BK)           // 25
#define BM 128
#define BN 128
#define CPB 2                  // 128-col chunks per block
#define NG 40                  // partial groups per row
#define NPAD (NG * 256)        // 10240
#define MARGIN 3.0f

typedef __attribute__((ext_vector_type(8))) short bh8;
typedef __attribute__((ext_vector_type(4))) float fx4;
typedef const __attribute__((address_space(1))) void CGV;
typedef __attribute__((address_space(3))) void LDSV;

static __device__ __forceinline__ unsigned short f2bf(float f) {
    unsigned u = __float_as_uint(f);
    unsigned r = u + 0x7fffu + ((u >> 16) & 1u);
    return (unsigned short)(r >> 16);
}

static __device__ __forceinline__ void top2_insert(float w, int j, float& v0, int& i0,
                                                   float& v1, int& i1) {
    if (w < v0 || (w == v0 && j < i0)) { v1 = v0; i1 = i0; v0 = w; i0 = j; }
    else if (w < v1 || (w == v1 && j < i1)) { v1 = w; i1 = j; }
}

// ---------------------------------------------------------------------------
__global__ __launch_bounds__(256) void convert_x_kernel(const float* __restrict__ x,
                                                        unsigned short* __restrict__ xh) {
    int row = blockIdx.x;
    const float4* xr = (const float4*)(x + (size_t)row * D);
    unsigned short* dst = xh + (size_t)row * KP;
    for (int i = threadIdx.x; i < KP / 4; i += 256) {
        int k = i * 4;
        uint2 o;
        if (k < D) {
            float4 v = xr[i];
            o.x = (unsigned)f2bf(v.x) | ((unsigned)f2bf(v.y) << 16);
            o.y = (unsigned)f2bf(v.z) | ((unsigned)f2bf(v.w) << 16);
        } else { o.x = 0u; o.y = 0u; }
        *(uint2*)(dst + k) = o;
    }
}

__global__ __launch_bounds__(256) void convert_w_kernel(const float* __restrict__ w,
                                                        unsigned short* __restrict__ wh,
                                                        float* __restrict__ wsq) {
    int row = blockIdx.x;
    unsigned short* dst = wh + (size_t)row * KP;
    float s = 0.f;
    if (row < N) {
        const float4* wr = (const float4*)(w + (size_t)row * D);
        for (int i = threadIdx.x; i < KP / 4; i += 256) {
            int k = i * 4;
            uint2 o;
            if (k < D) {
                float4 v = wr[i];
                s += v.x * v.x + v.y * v.y + v.z * v.z + v.w * v.w;
                o.x = (unsigned)f2bf(v.x) | ((unsigned)f2bf(v.y) << 16);
                o.y = (unsigned)f2bf(v.z) | ((unsigned)f2bf(v.w) << 16);
            } else { o.x = 0u; o.y = 0u; }
            *(uint2*)(dst + k) = o;
        }
    } else {
        for (int i = threadIdx.x; i < KP / 4; i += 256) {
            uint2 o; o.x = 0u; o.y = 0u;
            *(uint2*)(dst + i * 4) = o;
        }
    }
    __shared__ float sred[4];
    #pragma unroll
    for (int off = 32; off; off >>= 1) s += __shfl_down(s, off);
    if ((threadIdx.x & 63) == 0) sred[threadIdx.x >> 6] = s;
    __syncthreads();
    if (threadIdx.x == 0) {
        float t = sred[0] + sred[1] + sred[2] + sred[3];
        wsq[row] = (row < N) ? t : INFINITY;
    }
}

// ---------------------------------------------------------------------------
// MFMA distance kernel, r3 K-loop verbatim, but ZERO persistent register
// state across chunks: per chunk the top-2 is folded directly from acc
// (short-lived locals) -> shuffle -> LDS red[row][wavehalf][chunk];
// one final combine -> partial. K-loop live set ~100 regs -> no spill.
// ---------------------------------------------------------------------------
__global__ __launch_bounds__(256, 2) void dist_mfma_kernel(
    const unsigned short* __restrict__ xh, const unsigned short* __restrict__ wh,
    const float* __restrict__ wsq, float4* __restrict__ partial) {
    __shared__ __align__(16) unsigned short As[2][BM * BK];   // 2 x 8 KB
    __shared__ __align__(16) unsigned short Bs[2][BN * BK];   // 2 x 8 KB
    __shared__ float4 red[BM][2][CPB];                        // 8 KB

    const int tid = threadIdx.x;
    const int lane = tid & 63;
    const int wid = tid >> 6;
    const int waveM = (wid >> 1) * 64;
    const int waveN = (wid & 1) * 64;

    // XCD remap (nwg=1280, bijective): XCD owns 4 row-panels, sweeps bx;
    // 4 consecutive slots share bx (B-panel L2 reuse).
    const int L = blockIdx.x + NG * blockIdx.y;
    const int xcd = L & 7;
    const int s = L >> 3;                // 0..159
    const int bx = s >> 2;               // 0..39
    const int by = xcd * 4 + (s & 3);    // 0..31
    const int rowBase = by * BM;
    const int colBase0 = bx * (CPB * BN);

    // staging: row = j*64 + rr, phys slot = tid&3, logical slot XOR-swizzled
    const int rr = tid >> 2;
    const int csw = (tid & 3) ^ ((rr >> 1) & 3);
    const unsigned short* aSrc0 = xh + (size_t)(rowBase + rr) * KP + csw * 8;
    const unsigned short* aSrc1 = aSrc0 + (size_t)64 * KP;

    char* ldsA0 = (char*)&As[0][0] + wid * 1024;
    char* ldsA1 = (char*)&As[1][0] + wid * 1024;
    char* ldsB0 = (char*)&Bs[0][0] + wid * 1024;
    char* ldsB1 = (char*)&Bs[1][0] + wid * 1024;

    // fragment read offsets (halves), swizzled to match staging
    int offA[4], offB[4];
    #pragma unroll
    for (int m = 0; m < 4; m++) {
        int r = waveM + m * 16 + (lane & 15);
        offA[m] = r * BK + (((lane >> 4) ^ ((r >> 1) & 3)) << 3);
    }
    #pragma unroll
    for (int n = 0; n < 4; n++) {
        int r = waveN + n * 16 + (lane & 15);
        offB[n] = r * BK + (((lane >> 4) ^ ((r >> 1) & 3)) << 3);
    }

#define STAGE(nb, k0)                                                                  \
    do {                                                                               \
        __builtin_amdgcn_global_load_lds((CGV*)(aSrc0 + (k0)), (LDSV*)(ldsA##nb), 16, 0, 0);        \
        __builtin_amdgcn_global_load_lds((CGV*)(aSrc1 + (k0)), (LDSV*)(ldsA##nb + 4096), 16, 0, 0); \
        __builtin_amdgcn_global_load_lds((CGV*)(bSrc0 + (k0)), (LDSV*)(ldsB##nb), 16, 0, 0);        \
        __builtin_amdgcn_global_load_lds((CGV*)(bSrc1 + (k0)), (LDSV*)(ldsB##nb + 4096), 16, 0, 0); \
    } while (0)

#define COMPUTE(nb)                                                                    \
    do {                                                                               \
        bh8 af[4], bf[4];                                                              \
        _Pragma("unroll")                                                              \
        for (int m = 0; m < 4; m++) af[m] = *(const bh8*)&As[nb][offA[m]];             \
        _Pragma("unroll")                                                              \
        for (int n = 0; n < 4; n++) bf[n] = *(const bh8*)&Bs[nb][offB[n]];             \
        _Pragma("unroll")                                                              \
        for (int m = 0; m < 4; m++)                                                    \
            _Pragma("unroll")                                                          \
            for (int n = 0; n < 4; n++)                                                \
                acc[m][n] = __builtin_amdgcn_mfma_f32_16x16x32_bf16(af[m], bf[n],      \
                                                                    acc[m][n], 0, 0, 0); \
    } while (0)

    #pragma unroll 1
    for (int c = 0; c < CPB; ++c) {
        const int colBase = colBase0 + c * BN;
        const unsigned short* bSrc0 = wh + (size_t)(colBase + rr) * KP + csw * 8;
        const unsigned short* bSrc1 = bSrc0 + (size_t)64 * KP;

        fx4 acc[4][4];
        #pragma unroll
        for (int m = 0; m < 4; m++)
            #pragma unroll
            for (int n = 0; n < 4; n++) acc[m][n] = (fx4)0.f;

        STAGE(0, 0);
        asm volatile("s_waitcnt vmcnt(0)" ::: "memory");
        __builtin_amdgcn_s_barrier();
        #pragma unroll 1
        for (int t = 0; t < KT - 1; t += 2) {   // KT=25 odd: stages tiles 1..24
            STAGE(1, (t + 1) * BK);
            COMPUTE(0);
            asm volatile("s_waitcnt vmcnt(0)" ::: "memory");
            __builtin_amdgcn_s_barrier();
            STAGE(0, (t + 2) * BK);
            COMPUTE(1);
            asm volatile("s_waitcnt vmcnt(0)" ::: "memory");
            __builtin_amdgcn_s_barrier();
        }
        COMPUTE(0);   // tile KT-1

        // ---- fold THIS chunk straight from acc (no persistent regs) ----
        const int cb = colBase + waveN + (lane & 15);
        #pragma unroll
        for (int m = 0; m < 4; m++) {
            #pragma unroll
            for (int r = 0; r < 4; r++) {
                float v0 = INFINITY, v1 = INFINITY;
                int i0 = 0x7fffffff, i1 = 0x7fffffff;
                #pragma unroll
                for (int n = 0; n < 4; n++) {
                    float dv = wsq[cb + n * 16] - 2.f * acc[m][n][r];
                    top2_insert(dv, cb + n * 16, v0, i0, v1, i1);
                }
                #pragma unroll
                for (int mask = 1; mask < 16; mask <<= 1) {
                    float w0 = __shfl_xor(v0, mask); int j0 = __shfl_xor(i0, mask);
                    float w1 = __shfl_xor(v1, mask); int j1 = __shfl_xor(i1, mask);
                    top2_insert(w0, j0, v0, i0, v1, i1);
                    top2_insert(w1, j1, v0, i0, v1, i1);
                }
                if ((lane & 15) == 0) {
                    int row_local = waveM + m * 16 + (lane >> 4) * 4 + r;
                    red[row_local][wid & 1][c] =
                        make_float4(v0, __int_as_float(i0), v1, __int_as_float(i1));
                }
            }
        }
        __syncthreads();   // LDS reads done + red written before next chunk
    }

#undef STAGE
#undef COMPUTE

    // final combine: 4 entries -> one partial per row
    if (tid < BM) {
        float4 p0 = red[tid][0][0];
        float v0 = p0.x, v1 = p0.z;
        int i0 = __float_as_int(p0.y), i1 = __float_as_int(p0.w);
        #pragma unroll
        for (int h = 0; h < 2; h++)
            #pragma unroll
            for (int c = 0; c < CPB; c++) {
                if (h == 0 && c == 0) continue;
                float4 p = red[tid][h][c];
                top2_insert(p.x, __float_as_int(p.y), v0, i0, v1, i1);
                top2_insert(p.z, __float_as_int(p.w), v0, i0, v1, i1);
            }
        partial[(size_t)(rowBase + tid) * NG + bx] =
            make_float4(v0, __int_as_float(i0), v1, __int_as_float(i1));
    }
}

// ---------------------------------------------------------------------------
// Rescue: fp64 rescore of all candidates within MARGIN of approx global min.
// ---------------------------------------------------------------------------
__global__ __launch_bounds__(256) void rescore_kernel(const float* __restrict__ x,
                                                      const float* __restrict__ w,
                                                      const float4* __restrict__ partial,
                                                      float* __restrict__ out, int ng) {
    int wid = threadIdx.x >> 6, lane = threadIdx.x & 63;
    int row = blockIdx.x * 4 + wid;
    __shared__ int s_cnt[4];
    __shared__ int s_cand[4][64];

    const float4* part = partial + (size_t)row * ng;

    float bv = INFINITY;
    for (int c = lane; c < ng; c += 64) bv = fminf(bv, part[c].x);
    #pragma unroll
    for (int mask = 1; mask < 64; mask <<= 1) bv = fminf(bv, __shfl_xor(bv, mask));
    float thr = bv + MARGIN;

    if (lane == 0) s_cnt[wid] = 0;
    __syncthreads();
    for (int c = lane; c < ng; c += 64) {
        float4 p = part[c];
        if (p.x <= thr) {
            int pos = atomicAdd(&s_cnt[wid], 1);
            if (pos < 64) s_cand[wid][pos] = __float_as_int(p.y);
        }
        if (p.z <= thr) {
            int pos = atomicAdd(&s_cnt[wid], 1);
            if (pos < 64) s_cand[wid][pos] = __float_as_int(p.w);
        }
    }
    __syncthreads();
    int cnt = s_cnt[wid]; if (cnt > 64) cnt = 64;

    double bd = INFINITY; int bi = 0x7fffffff;
    for (int c = 0; c < cnt; c++) {
        int idx = s_cand[wid][c];
        const float* wr = w + (size_t)idx * D;
        const float* xr = x + (size_t)row * D;
        double s = 0.0;
        for (int d = lane; d < D; d += 64) {
            double wv = (double)wr[d];
            s += wv * (wv - 2.0 * (double)xr[d]);
        }
        #pragma unroll
        for (int mask = 1; mask < 64; mask <<= 1) s += __shfl_xor(s, mask);
        if (s < bd || (s == bd && idx < bi)) { bd = s; bi = idx; }
    }

    const float4* src = (const float4*)(w + (size_t)bi * D);
    float4* dst = (float4*)(out + (size_t)row * D);
    for (int i = lane; i < D / 4; i += 64) dst[i] = src[i];
}

// ---------------------------------------------------------------------------
extern "C" void kernel_launch(void* const* d_in, const int* in_sizes, int n_in,
                              void* d_out, int out_size, void* d_ws, size_t ws_size,
                              hipStream_t stream) {
    const float* x = (const float*)d_in[0];
    const float* w = (const float*)d_in[1];
    float* out = (float*)d_out;

    const size_t off_xh = 0;
    const size_t off_wh = off_xh + (size_t)BATCH * KP * 2;     // 6,553,600
    const size_t off_wsq = off_wh + (size_t)NPAD * KP * 2;     // +16,384,000
    const size_t off_part = off_wsq + (size_t)NPAD * 4;        // +40,960
    // need = off_part + 4096*40*16 = 25,600,000 B (exact r7-proven footprint)

    unsigned short* xh = (unsigned short*)((char*)d_ws + off_xh);
    unsigned short* wh = (unsigned short*)((char*)d_ws + off_wh);
    float* wsq = (float*)((char*)d_ws + off_wsq);
    float4* partial = (float4*)((char*)d_ws + off_part);

    hipLaunchKernelGGL(convert_x_kernel, dim3(BATCH), dim3(256), 0, stream, x, xh);
    hipLaunchKernelGGL(convert_w_kernel, dim3(NPAD), dim3(256), 0, stream, w, wh, wsq);
    hipLaunchKernelGGL(dist_mfma_kernel, dim3(NG, 32), dim3(256), 0, stream,
                       xh, wh, wsq, partial);
    hipLaunchKernelGGL(rescore_kernel, dim3(BATCH / 4), dim3(256), 0, stream,
                       x, w, partial, out, NG);
}